// Round 2
// baseline (5309.702 us; speedup 1.0000x reference)
//
#include <hip/hip_runtime.h>

typedef _Float16 f16;
typedef _Float16 f16x8 __attribute__((ext_vector_type(8)));
typedef float    f32x4 __attribute__((ext_vector_type(4)));

#define MFMA_F16(A, B, C) __builtin_amdgcn_mfma_f32_16x16x32_f16((A), (B), (C), 0, 0, 0)

// A-fragment LDS layout: [kb][slot 0..63][j 0..7] f16, slot s = (m&15) + 16*((k>>3)&3),
// j = k&7.  XOR swizzle spreads the kb-stride (1024B, bank-invariant) and the q-stride
// (256B) across banks; read side (slot == lane) stays a bijective permutation of a
// contiguous 1KB block => conflict-free ds_read_b128.
__device__ __forceinline__ int frag_slot(int kb, int s) {
  return s ^ (kb & 7) ^ (((s >> 4) & 3) << 1);
}

// ---------------------------------------------------------------------------
// prep: convert weights fp32 -> fp16 into ws, combine biases
// ---------------------------------------------------------------------------
__global__ void prep_kernel(const float* __restrict__ Wih0, const float* __restrict__ Whh0,
                            const float* __restrict__ Wih1, const float* __restrict__ Whh1,
                            const float* __restrict__ bih0, const float* __restrict__ bhh0,
                            const float* __restrict__ bih1, const float* __restrict__ bhh1,
                            f16* __restrict__ wdst, float* __restrict__ b0, float* __restrict__ b1)
{
  if (blockIdx.x == 224) {
    const int i = threadIdx.x;  // 256 threads
    b0[i] = bih0[i] + bhh0[i];
    b1[i] = bih1[i] + bhh1[i];
    return;
  }
  const int idx = blockIdx.x * 256 + threadIdx.x;
  const int i4 = idx * 4;
  const float* src; int off;
  if (i4 < 32768)       { src = Wih0; off = i4; }
  else if (i4 < 98304)  { src = Whh0; off = i4 - 32768; }
  else if (i4 < 163840) { src = Wih1; off = i4 - 98304; }
  else                  { src = Whh1; off = i4 - 163840; }
  const float4 v = *(const float4*)(src + off);
  union { f16 h[4]; uint2 u; } cv;
  cv.h[0] = (f16)v.x; cv.h[1] = (f16)v.y; cv.h[2] = (f16)v.z; cv.h[3] = (f16)v.w;
  *(uint2*)(wdst + i4) = cv.u;
}

// ---------------------------------------------------------------------------
// gemm_proj: out[t][b][h] (f16) = A @ W^T + bias
// MODE 0: A = x fp32 [B=64][T=2048][128], KK=128, block = (b, 64-t block)
// MODE 1: A = h1 f16 [T*B][256],         KK=256, block = 64 consecutive rows
//         (may run IN PLACE: A-tile fully staged to LDS before any store,
//          and blocks touch disjoint row ranges)
// Per WG: 64 rows x 256 cols, 4 waves, wave w owns cols [w*64, w*64+64)
// ---------------------------------------------------------------------------
template<int KK, int MODE>
__global__ __launch_bounds__(256, 2)
void gemm_proj(const void* Asrc, const f16* __restrict__ W,
               const float* __restrict__ bias, f16* outp)
{
  constexpr int NKB = KK / 32;
  __shared__ f16 sA[4 * NKB * 512];  // [mt][kb][slot][j]

  const int tid  = threadIdx.x;
  const int lane = tid & 63;
  const int wv   = tid >> 6;
  const int l15  = lane & 15;
  const int l4   = lane >> 4;
  const int bid  = blockIdx.x;

  int b = 0, tblk = 0, m0 = 0;
  if constexpr (MODE == 0) { b = bid >> 5; tblk = bid & 31; }
  else                     { m0 = bid * 64; }

  if constexpr (MODE == 0) {
    const float* x = (const float*)Asrc;
    const int k4 = tid & 31, rblk = tid >> 5;
#pragma unroll
    for (int ii = 0; ii < 8; ++ii) {
      const int row = rblk * 8 + ii;
      const float4 v = *(const float4*)(x + (size_t)(b * 2048 + tblk * 64 + row) * 128 + k4 * 4);
      const int k  = k4 * 4;
      const int kb = k >> 5;
      const int s  = (row & 15) + 16 * ((k >> 3) & 3);
      const int mt = row >> 4;
      union { f16 h[4]; uint2 u; } cv;
      cv.h[0] = (f16)v.x; cv.h[1] = (f16)v.y; cv.h[2] = (f16)v.z; cv.h[3] = (f16)v.w;
      *(uint2*)&sA[mt * (NKB * 512) + kb * 512 + frag_slot(kb, s) * 8 + (k & 7)] = cv.u;
    }
  } else {
    const f16* h1 = (const f16*)Asrc;
    const int k8 = tid & 31, rblk = tid >> 5;
#pragma unroll
    for (int ii = 0; ii < 8; ++ii) {
      const int row = rblk * 8 + ii;
      const f16x8 v = *(const f16x8*)(h1 + (size_t)(m0 + row) * 256 + k8 * 8);
      const int k  = k8 * 8;
      const int kb = k >> 5;
      const int s  = (row & 15) + 16 * ((k >> 3) & 3);
      const int mt = row >> 4;
      *(f16x8*)&sA[mt * (NKB * 512) + kb * 512 + frag_slot(kb, s) * 8] = v;
    }
  }
  __syncthreads();

  // W fragments (B-operand): lane holds W[n][k], n = wv*64+t16*16+l15, k = kb*32+l4*8..+8
  f16x8 wf[4][NKB];
#pragma unroll
  for (int t16 = 0; t16 < 4; ++t16) {
    const int n = wv * 64 + t16 * 16 + l15;
#pragma unroll
    for (int kb = 0; kb < NKB; ++kb)
      wf[t16][kb] = *(const f16x8*)(W + (size_t)n * KK + kb * 32 + l4 * 8);
  }

  f32x4 acc[4][4];
#pragma unroll
  for (int mt = 0; mt < 4; ++mt)
#pragma unroll
    for (int t16 = 0; t16 < 4; ++t16)
      acc[mt][t16] = f32x4{0.f, 0.f, 0.f, 0.f};

#pragma unroll
  for (int kb = 0; kb < NKB; ++kb)
#pragma unroll
    for (int mt = 0; mt < 4; ++mt) {
      const f16x8 a = *(const f16x8*)&sA[mt * (NKB * 512) + kb * 512 + frag_slot(kb, lane) * 8];
#pragma unroll
      for (int t16 = 0; t16 < 4; ++t16)
        acc[mt][t16] = MFMA_F16(a, wf[t16][kb], acc[mt][t16]);
    }

#pragma unroll
  for (int t16 = 0; t16 < 4; ++t16) {
    const int col = wv * 64 + t16 * 16 + l15;
    const float bb = bias[col];
#pragma unroll
    for (int mt = 0; mt < 4; ++mt)
#pragma unroll
      for (int r = 0; r < 4; ++r) {
        const float vv = acc[mt][t16][r] + bb;
        const int row = mt * 16 + l4 * 4 + r;
        size_t off;
        if constexpr (MODE == 0) off = (size_t)(tblk * 64 + row) * 16384 + (size_t)b * 256 + col;
        else                     off = (size_t)(m0 + row) * 256 + col;
        outp[off] = (f16)vv;
      }
  }
}

// ---------------------------------------------------------------------------
// rnn_rec: h_t = tanh(pre[t] + h_{t-1} @ Whh^T), 4 WGs x 16 batches, 4 waves.
// Whh fragments live in VGPRs (128/lane); h state double-buffered in LDS in
// A-fragment layout.  One s_barrier per step, lgkmcnt-only wait (no vmcnt
// drain, so pre-prefetch (2 steps ahead) and h stores stay in flight).
// WRITE_H may alias hout == pre (in place): WG g only touches batch slice g;
// slot t's last read (step t-2, waited before use at step t) precedes its
// write (step t) in program order within the same wave.
// ---------------------------------------------------------------------------
template<bool WRITE_H>
__global__ __launch_bounds__(256, 1)
void rnn_rec(const f16* pre,                 // [T][64][256]
             const f16* __restrict__ Whh,    // [256][256] f16 row-major
             f16* hout,                      // [T][64][256] (WRITE_H; may == pre)
             float* __restrict__ hlast)      // [64][256] (!WRITE_H)
{
  __shared__ f16 sH[8192];  // 2 buffers x (8 kb x 64 slots x 8)
  const int tid  = threadIdx.x;
  const int lane = tid & 63;
  const int wv   = tid >> 6;
  const int l15  = lane & 15;
  const int l4   = lane >> 4;
  const int g16  = blockIdx.x * 16;   // batch base

  for (int i = tid; i < 4096; i += 256) ((unsigned int*)sH)[i] = 0u;  // h_{-1} = 0

  f16x8 wf[4][8];
#pragma unroll
  for (int t16 = 0; t16 < 4; ++t16) {
    const int n = wv * 64 + t16 * 16 + l15;
#pragma unroll
    for (int kb = 0; kb < 8; ++kb)
      wf[t16][kb] = *(const f16x8*)(Whh + (size_t)n * 256 + kb * 32 + l4 * 8);
  }

  f16 pA[16], pB[16];
#pragma unroll
  for (int t16 = 0; t16 < 4; ++t16)
#pragma unroll
    for (int r = 0; r < 4; ++r) {
      const int row = l4 * 4 + r;
      const int col = wv * 64 + t16 * 16 + l15;
      pA[t16 * 4 + r] = pre[(size_t)(g16 + row) * 256 + col];
      pB[t16 * 4 + r] = pre[16384 + (size_t)(g16 + row) * 256 + col];
    }

  __syncthreads();

  auto step = [&](int t, int rd, int wr, f16 (&pc)[16]) {
    f32x4 acc[4];
#pragma unroll
    for (int i = 0; i < 4; ++i) acc[i] = f32x4{0.f, 0.f, 0.f, 0.f};
#pragma unroll
    for (int kb = 0; kb < 8; ++kb) {
      const f16x8 a = *(const f16x8*)&sH[rd + kb * 512 + frag_slot(kb, lane) * 8];
#pragma unroll
      for (int t16 = 0; t16 < 4; ++t16)
        acc[t16] = MFMA_F16(a, wf[t16][kb], acc[t16]);
    }
    float z[16];
#pragma unroll
    for (int t16 = 0; t16 < 4; ++t16)
#pragma unroll
      for (int r = 0; r < 4; ++r)
        z[t16 * 4 + r] = acc[t16][r] + (float)pc[t16 * 4 + r];
    // prefetch pre[t+2] into the just-freed register buffer (distance 2 steps
    // covers HBM latency); skipped at the tail (also avoids any same-address
    // load/store overlap when hout aliases pre)
    if (t + 2 < 2048) {
      const f16* pp = pre + (size_t)(t + 2) * 16384 + (size_t)g16 * 256;
#pragma unroll
      for (int t16 = 0; t16 < 4; ++t16)
#pragma unroll
        for (int r = 0; r < 4; ++r)
          pc[t16 * 4 + r] = pp[(l4 * 4 + r) * 256 + wv * 64 + t16 * 16 + l15];
    }
#pragma unroll
    for (int t16 = 0; t16 < 4; ++t16) {
      const int col = wv * 64 + t16 * 16 + l15;
      const int kb2 = col >> 5;
      const int s2b = 16 * ((col >> 3) & 3);
#pragma unroll
      for (int r = 0; r < 4; ++r) {
        const float zz = z[t16 * 4 + r];
        const float e  = __expf(zz + zz);                                // exp(2z)
        const float hv = 1.0f - 2.0f * __builtin_amdgcn_rcpf(e + 1.0f);  // tanh(z)
        const f16 h16  = (f16)hv;
        sH[wr + kb2 * 512 + frag_slot(kb2, l4 * 4 + r + s2b) * 8 + (col & 7)] = h16;
        if constexpr (WRITE_H) {
          hout[(size_t)t * 16384 + (size_t)(g16 + l4 * 4 + r) * 256 + col] = h16;
        } else {
          if (t == 2047) hlast[(size_t)(g16 + l4 * 4 + r) * 256 + col] = hv;
        }
      }
    }
    // barrier with LDS-only drain: keep global loads/stores in flight
    asm volatile("s_waitcnt lgkmcnt(0)" ::: "memory");
    __builtin_amdgcn_sched_barrier(0);
    __builtin_amdgcn_s_barrier();
    __builtin_amdgcn_sched_barrier(0);
  };

#pragma unroll 1
  for (int t = 0; t < 2048; t += 2) {
    step(t,     0,    4096, pA);
    step(t + 1, 4096, 0,    pB);
  }
}

// ---------------------------------------------------------------------------
// fc: out[b][o] = h2last[b] . fc_w[o] + fc_b[o]
// ---------------------------------------------------------------------------
__global__ void fc_kernel(const float* __restrict__ h, const float* __restrict__ W,
                          const float* __restrict__ bvec, float* __restrict__ out)
{
  const int idx = blockIdx.x * 256 + threadIdx.x;  // 8192
  const int bb = idx >> 7, o = idx & 127;
  const float4* hp = (const float4*)(h + bb * 256);
  const float4* wp = (const float4*)(W + o * 256);
  float acc = 0.f;
#pragma unroll
  for (int i = 0; i < 64; ++i) {
    const float4 a = hp[i], c = wp[i];
    acc += a.x * c.x + a.y * c.y + a.z * c.z + a.w * c.w;
  }
  out[idx] = acc + bvec[o];
}

// ---------------------------------------------------------------------------
extern "C" void kernel_launch(void* const* d_in, const int* in_sizes, int n_in,
                              void* d_out, int out_size, void* d_ws, size_t ws_size,
                              hipStream_t stream)
{
  const float* x    = (const float*)d_in[0];
  const float* Wih0 = (const float*)d_in[1];
  const float* Whh0 = (const float*)d_in[2];
  const float* bih0 = (const float*)d_in[3];
  const float* bhh0 = (const float*)d_in[4];
  const float* Wih1 = (const float*)d_in[5];
  const float* Whh1 = (const float*)d_in[6];
  const float* bih1 = (const float*)d_in[7];
  const float* bhh1 = (const float*)d_in[8];
  const float* fcw  = (const float*)d_in[9];
  const float* fcb  = (const float*)d_in[10];
  float* out = (float*)d_out;

  // Lean workspace plan (~64.5 MB total):
  char* ws = (char*)d_ws;
  f16*   Wih0h  = (f16*)(ws);                    // 64 KB (base for all 4 matrices)
  f16*   Whh0h  = (f16*)(ws + 65536);            // 128 KB
  f16*   Wih1h  = (f16*)(ws + 196608);           // 128 KB
  f16*   Whh1h  = (f16*)(ws + 327680);           // 128 KB
  float* b0     = (float*)(ws + 458752);         // 1 KB
  float* b1     = (float*)(ws + 459776);         // 1 KB
  float* h2last = (float*)(ws + 460800);         // 64 KB
  f16*   buf    = (f16*)(ws + 526336);           // 64 MiB: pre0 -> h1 -> pre1 (in place)

  prep_kernel<<<225, 256, 0, stream>>>(Wih0, Whh0, Wih1, Whh1, bih0, bhh0, bih1, bhh1,
                                       Wih0h, b0, b1);
  gemm_proj<128, 0><<<2048, 256, 0, stream>>>(x,   Wih0h, b0, buf);   // pre0
  rnn_rec<true ><<<4, 256, 0, stream>>>(buf, Whh0h, buf, nullptr);    // h1 over pre0
  gemm_proj<256, 1><<<2048, 256, 0, stream>>>(buf, Wih1h, b1, buf);   // pre1 over h1
  rnn_rec<false><<<4, 256, 0, stream>>>(buf, Whh1h, nullptr, h2last);
  fc_kernel<<<32, 256, 0, stream>>>(h2last, fcw, fcb, out);
}

// Round 6
// 3299.029 us; speedup vs baseline: 1.6095x; 1.6095x over previous
//
#include <hip/hip_runtime.h>

typedef _Float16 f16;
typedef _Float16 f16x4 __attribute__((ext_vector_type(4)));
typedef _Float16 f16x8 __attribute__((ext_vector_type(8)));
typedef __fp16   fp16x2 __attribute__((ext_vector_type(2)));
typedef float    f32x4 __attribute__((ext_vector_type(4)));

#define MFMA_F16(A,B,C) __builtin_amdgcn_mfma_f32_16x16x32_f16((A),(B),(C),0,0,0)

// 2*log2(e): pre-activation is stored pre-scaled by this, so tanh(z) needs only
// exp2: z2 = acc*C2 + preC;  tanh = 1 - 2*rcp(exp2(z2)+1)
#define C2F 2.885390081777927f

// pack 4 floats -> f16x4 via two v_cvt_pkrtz_f16_f32 (bit-identical reinterpret)
__device__ __forceinline__ f16x4 pk4(float a, float b, float c, float d) {
  union { fp16x2 p[2]; f16x4 v; } u;
  u.p[0] = __builtin_amdgcn_cvt_pkrtz(a, b);
  u.p[1] = __builtin_amdgcn_cvt_pkrtz(c, d);
  return u.v;
}

// Physical LDS slot permutation: spreads the b64-write bank pattern while the
// b128 read side (16-lane phases, 16B/lane) stays a bijective slot permutation
// => conflict-free reads.  Bijective XOR of bits{3,4} into bits{2,1}.
__device__ __forceinline__ int pslot(int s) {
  return s ^ (((s >> 3) & 1) << 2) ^ (((s >> 4) & 1) << 1);
}

// Global fragment-pack layout P for pre/h1 (f16):
//   elem(t, b, col) -> t*16384 + (col>>2)*256 + b*4 + (col&3)
// A lane's 4 consecutive cols for one batch = one aligned 8B pack.

// ---------------------------------------------------------------------------
// prep: weights fp32 -> fp16 (row-major), biases combined AND scaled by C2
// ---------------------------------------------------------------------------
__global__ void prep_kernel(const float* __restrict__ Wih0, const float* __restrict__ Whh0,
                            const float* __restrict__ Wih1, const float* __restrict__ Whh1,
                            const float* __restrict__ bih0, const float* __restrict__ bhh0,
                            const float* __restrict__ bih1, const float* __restrict__ bhh1,
                            f16* __restrict__ wdst, float* __restrict__ b0C, float* __restrict__ b1C)
{
  if (blockIdx.x == 224) {
    const int i = threadIdx.x;  // 256 threads
    b0C[i] = (bih0[i] + bhh0[i]) * C2F;
    b1C[i] = (bih1[i] + bhh1[i]) * C2F;
    return;
  }
  const int i4 = (blockIdx.x * 256 + threadIdx.x) * 4;
  const float* src; int off;
  if (i4 < 32768)       { src = Wih0; off = i4; }
  else if (i4 < 98304)  { src = Whh0; off = i4 - 32768; }
  else if (i4 < 163840) { src = Wih1; off = i4 - 98304; }
  else                  { src = Whh1; off = i4 - 163840; }
  const float4 v = *(const float4*)(src + off);
  *(f16x4*)(wdst + i4) = pk4(v.x, v.y, v.z, v.w);
}

// ---------------------------------------------------------------------------
// gemm_proj (swapped operands: A = W rows=outcol, B = input rows): computes
// preC = (inp @ W^T + bias) * C2, stored in P layout (f16).
// MODE 0: inp = x fp32 [64 b][2048 t][128]; block = (b, 64-t tile); KK=128
// MODE 1: inp = h1 (P layout f16), one t-slice per block; KK=256; IN PLACE OK
//         (whole slice staged to LDS before any store; blocks touch disjoint t)
// Per WG: 64 rows x 256 outcols, 4 waves; wave wv owns outcols [wv*64,+64)
// ---------------------------------------------------------------------------
template<int KK, int MODE>
__global__ __launch_bounds__(256, 2)
void gemm_proj(const void* Asrc, const f16* __restrict__ W,
               const float* __restrict__ biasC, f16* outp)
{
  constexpr int NKB = KK / 32;
  __shared__ f16 sB[4 * NKB * 512];  // [rt 0..3][kb][slot 0..63][j8] (linear slots)

  const int tid = threadIdx.x, lane = tid & 63, wv = tid >> 6;
  const int l15 = lane & 15, l4 = lane >> 4;
  const int bid = blockIdx.x;

  if constexpr (MODE == 0) {
    // rows = 64 consecutive t for batch b; stage fp32 -> f16 B-frags
    const float* x = (const float*)Asrc + ((size_t)(bid >> 5) * 2048 + (size_t)(bid & 31) * 64) * 128;
    const int rp = tid >> 3, kg = tid & 7;   // rows 2rp,2rp+1 ; k = kg*16..+15
#pragma unroll
    for (int rr = 0; rr < 2; ++rr) {
      const int row = rp * 2 + rr;
      const float* xr = x + (size_t)row * 128 + kg * 16;
#pragma unroll
      for (int c4 = 0; c4 < 4; ++c4) {
        const float4 v = *(const float4*)(xr + c4 * 4);
        const int k = kg * 16 + c4 * 4;
        const int rt = row >> 4, kb = k >> 5;
        const int slot = (row & 15) + 16 * ((k >> 3) & 3);
        *(f16x4*)&sB[rt * (NKB * 512) + kb * 512 + slot * 8 + (k & 7)] = pk4(v.x, v.y, v.z, v.w);
      }
    }
  } else {
    // one t-slice (16384 f16 = 32KB) in P layout; rows = 64 batches
    const f16* hp = (const f16*)Asrc + (size_t)bid * 16384;
#pragma unroll
    for (int it = 0; it < 8; ++it) {
      const int o = tid * 8 + it * 2048;       // f16 elems; 8 elems = 2 packs
      const f16x8 v = *(const f16x8*)(hp + o);
      const int cp = o >> 8;                   // colpack
      const int b0 = (o >> 2) & 63;            // even; covers b0, b0+1
      const int k0 = cp * 4;
      const int kb = k0 >> 5;
      const int jo = k0 & 7;                   // 0 or 4
      const int qq = (k0 >> 3) & 3;
      f16x4 lo; lo.x = v[0]; lo.y = v[1]; lo.z = v[2]; lo.w = v[3];
      f16x4 hi; hi.x = v[4]; hi.y = v[5]; hi.z = v[6]; hi.w = v[7];
      const int s0 = ((b0 & 15) + 16 * qq), rt0 = b0 >> 4;
      const int s1 = (((b0 + 1) & 15) + 16 * qq), rt1 = (b0 + 1) >> 4;
      *(f16x4*)&sB[rt0 * (NKB * 512) + kb * 512 + s0 * 8 + jo] = lo;
      *(f16x4*)&sB[rt1 * (NKB * 512) + kb * 512 + s1 * 8 + jo] = hi;
    }
  }
  __syncthreads();

  // A-frags: lane holds W[outcol = base+ct*16+l15][k = kb*32 + l4*8 ..+7]
  f16x8 wa[4][NKB];
#pragma unroll
  for (int ct = 0; ct < 4; ++ct) {
    const int oc = wv * 64 + ct * 16 + l15;
#pragma unroll
    for (int kb = 0; kb < NKB; ++kb)
      wa[ct][kb] = *(const f16x8*)(W + (size_t)oc * KK + kb * 32 + l4 * 8);
  }
  float bC[4][4];
#pragma unroll
  for (int ct = 0; ct < 4; ++ct)
#pragma unroll
    for (int r = 0; r < 4; ++r)
      bC[ct][r] = biasC[wv * 64 + ct * 16 + l4 * 4 + r];

  f32x4 acc[4][4];  // [ct][rt]
#pragma unroll
  for (int ct = 0; ct < 4; ++ct)
#pragma unroll
    for (int rt = 0; rt < 4; ++rt)
      acc[ct][rt] = f32x4{0.f, 0.f, 0.f, 0.f};

#pragma unroll
  for (int kb = 0; kb < NKB; ++kb)
#pragma unroll
    for (int rt = 0; rt < 4; ++rt) {
      const f16x8 hb = *(const f16x8*)&sB[rt * (NKB * 512) + kb * 512 + lane * 8];
#pragma unroll
      for (int ct = 0; ct < 4; ++ct)
        acc[ct][rt] = MFMA_F16(wa[ct][kb], hb, acc[ct][rt]);
    }

  // epilogue: C[m=outcol][n=row]; lane holds outcols ct*16+l4*4+r for row rt*16+l15
#pragma unroll
  for (int rt = 0; rt < 4; ++rt) {
    const int rown = rt * 16 + l15;
    size_t base;  // f16 elems into P
    if constexpr (MODE == 0) base = ((size_t)(bid & 31) * 64 + rown) * 16384 + (size_t)(bid >> 5) * 4;
    else                     base = (size_t)bid * 16384 + (size_t)rown * 4;
#pragma unroll
    for (int ct = 0; ct < 4; ++ct) {
      const int cp = wv * 16 + ct * 4 + l4;
      const float v0 = fmaf(acc[ct][rt][0], C2F, bC[ct][0]);
      const float v1 = fmaf(acc[ct][rt][1], C2F, bC[ct][1]);
      const float v2 = fmaf(acc[ct][rt][2], C2F, bC[ct][2]);
      const float v3 = fmaf(acc[ct][rt][3], C2F, bC[ct][3]);
      *(f16x4*)(outp + base + (size_t)cp * 256) = pk4(v0, v1, v2, v3);
    }
  }
}

// ---------------------------------------------------------------------------
// rnn_rec: h_t = tanh-from-exp2(pre[t], h_{t-1} @ Whh^T).  4 WGs x 16 batches,
// 4 waves; wave owns 64 outcols.  Swapped MFMA: A = Whh frags (VGPR-resident),
// B = h frags from LDS (linear b128 reads, pslot-permuted slots).  Epilogue:
// packed cvt_pkrtz -> 4 ds_write_b64 + 4 global 8B stores (LAYER 0) with
// precomputed lane addresses.  pre prefetched 2 steps ahead.  One s_barrier
// per step with lgkmcnt-only drain (global ops stay in flight).
// LAYER 0: hout may alias pre (in-place h1 over pre0).
// ---------------------------------------------------------------------------
template<int LAYER>
__global__ __launch_bounds__(256, 1)
void rnn_rec(const f16* pre,                // P layout [T][cp][b][4]
             const f16* __restrict__ Whh,   // [256][256] f16 row-major
             f16* hout,                     // P layout (LAYER 0; may == pre)
             float* __restrict__ hlast)     // [64][256] f32 (LAYER 1)
{
  __shared__ f16 sH[8192];  // 2 buffers x [8 kb][64 pslot][8 f16]
  const int tid = threadIdx.x, lane = tid & 63, wv = tid >> 6;
  const int l15 = lane & 15, l4 = lane >> 4;
  const int g16 = blockIdx.x * 16;

  for (int i = tid; i < 2048; i += 256) ((unsigned int*)sH)[i] = 0u;  // h_{-1}=0 (buf0)

  // Whh A-frags, VGPR-resident: lane holds Whh[wv*64+ct*16+l15][kb*32+l4*8 ..+7]
  f16x8 wa[4][8];
#pragma unroll
  for (int ct = 0; ct < 4; ++ct) {
    const int oc = wv * 64 + ct * 16 + l15;
#pragma unroll
    for (int kb = 0; kb < 8; ++kb)
      wa[ct][kb] = *(const f16x8*)(Whh + (size_t)oc * 256 + kb * 32 + l4 * 8);
  }

  // LDS write offsets (f16 elems): kb' = wv*2 + (ct>>1); q = (ct&1)*2 + (l4>>1);
  // addr = kb'*512 + pslot(l15+16q)*8 + (l4&1)*4   (+ parity, + (ct>>1)*512)
  int woff[2];
#pragma unroll
  for (int c1 = 0; c1 < 2; ++c1) {
    const int q = c1 * 2 + (l4 >> 1);
    woff[c1] = wv * 1024 + pslot(l15 + 16 * q) * 8 + (l4 & 1) * 4;
  }
  const int roff = pslot(lane) * 8;

  // global P lane offset (f16 elems): cp = wv*16 + ct*4 + l4, b = g16+l15
  const int laneP = (wv * 16 + l4) * 256 + (g16 + l15) * 4;  // + ct*1024 + t*16384

  f16x4 pA[4], pB[4];
#pragma unroll
  for (int ct = 0; ct < 4; ++ct) {
    pA[ct] = *(const f16x4*)(pre + laneP + ct * 1024);            // t=0
    pB[ct] = *(const f16x4*)(pre + 16384 + laneP + ct * 1024);    // t=1
  }
  __syncthreads();

  auto step = [&](int t, int rdo, int wro, f16x4 (&pc)[4], bool last) {
    f32x4 acc[4];
#pragma unroll
    for (int i = 0; i < 4; ++i) acc[i] = f32x4{0.f, 0.f, 0.f, 0.f};
#pragma unroll
    for (int kb = 0; kb < 8; ++kb) {
      const f16x8 hb = *(const f16x8*)&sH[rdo + kb * 512 + roff];
#pragma unroll
      for (int ct = 0; ct < 4; ++ct)
        acc[ct] = MFMA_F16(wa[ct][kb], hb, acc[ct]);
    }
    // consume pre into z2, then refill pc with pre[t+2] (loads issued early)
    float z2[4][4];
#pragma unroll
    for (int ct = 0; ct < 4; ++ct)
#pragma unroll
      for (int r = 0; r < 4; ++r)
        z2[ct][r] = fmaf(acc[ct][r], C2F, (float)pc[ct][r]);
    if (t + 2 < 2048) {
#pragma unroll
      for (int ct = 0; ct < 4; ++ct)
        pc[ct] = *(const f16x4*)(pre + (size_t)(t + 2) * 16384 + laneP + ct * 1024);
    }
#pragma unroll
    for (int ct = 0; ct < 4; ++ct) {
      float h[4];
#pragma unroll
      for (int r = 0; r < 4; ++r) {
        const float e = __builtin_amdgcn_exp2f(z2[ct][r]);
        h[r] = fmaf(__builtin_amdgcn_rcpf(e + 1.0f), -2.0f, 1.0f);
      }
      const f16x4 pk = pk4(h[0], h[1], h[2], h[3]);
      *(f16x4*)&sH[wro + (ct >> 1) * 512 + woff[ct & 1]] = pk;
      if constexpr (LAYER == 0) {
        *(f16x4*)(hout + (size_t)t * 16384 + laneP + ct * 1024) = pk;
      } else {
        if (last) {
#pragma unroll
          for (int r = 0; r < 4; ++r)
            hlast[(g16 + l15) * 256 + wv * 64 + ct * 16 + l4 * 4 + r] = h[r];
        }
      }
    }
    // LDS-only drain before barrier: global loads/stores stay in flight
    asm volatile("s_waitcnt lgkmcnt(0)" ::: "memory");
    __builtin_amdgcn_sched_barrier(0);
    __builtin_amdgcn_s_barrier();
    __builtin_amdgcn_sched_barrier(0);
  };

#pragma unroll 1
  for (int t = 0; t < 2048; t += 2) {
    step(t,     0,    4096, pA, false);
    step(t + 1, 4096, 0,    pB, t + 1 == 2047);
  }
}

// ---------------------------------------------------------------------------
// fc: out[b][o] = h2last[b] . fc_w[o] + fc_b[o]
// ---------------------------------------------------------------------------
__global__ void fc_kernel(const float* __restrict__ h, const float* __restrict__ W,
                          const float* __restrict__ bvec, float* __restrict__ out)
{
  const int idx = blockIdx.x * 256 + threadIdx.x;  // 8192
  const int bb = idx >> 7, o = idx & 127;
  const float4* hp = (const float4*)(h + bb * 256);
  const float4* wp = (const float4*)(W + o * 256);
  float acc = 0.f;
#pragma unroll
  for (int i = 0; i < 64; ++i) {
    const float4 a = hp[i], c = wp[i];
    acc += a.x * c.x + a.y * c.y + a.z * c.z + a.w * c.w;
  }
  out[idx] = acc + bvec[o];
}

// ---------------------------------------------------------------------------
extern "C" void kernel_launch(void* const* d_in, const int* in_sizes, int n_in,
                              void* d_out, int out_size, void* d_ws, size_t ws_size,
                              hipStream_t stream)
{
  const float* x    = (const float*)d_in[0];
  const float* Wih0 = (const float*)d_in[1];
  const float* Whh0 = (const float*)d_in[2];
  const float* bih0 = (const float*)d_in[3];
  const float* bhh0 = (const float*)d_in[4];
  const float* Wih1 = (const float*)d_in[5];
  const float* Whh1 = (const float*)d_in[6];
  const float* bih1 = (const float*)d_in[7];
  const float* bhh1 = (const float*)d_in[8];
  const float* fcw  = (const float*)d_in[9];
  const float* fcb  = (const float*)d_in[10];
  float* out = (float*)d_out;

  // Workspace plan (~64.5 MB total)
  char* ws = (char*)d_ws;
  f16*   Wih0h  = (f16*)(ws);             // 64 KB (base for all 4 matrices)
  f16*   Whh0h  = (f16*)(ws + 65536);     // 128 KB
  f16*   Wih1h  = (f16*)(ws + 196608);    // 128 KB
  f16*   Whh1h  = (f16*)(ws + 327680);    // 128 KB
  float* b0C    = (float*)(ws + 458752);  // 1 KB
  float* b1C    = (float*)(ws + 459776);  // 1 KB
  float* h2last = (float*)(ws + 460800);  // 64 KB
  f16*   buf    = (f16*)(ws + 526336);    // 64 MiB: pre0 -> h1 -> pre1 (in place)

  prep_kernel<<<225, 256, 0, stream>>>(Wih0, Whh0, Wih1, Whh1, bih0, bhh0, bih1, bhh1,
                                       Wih0h, b0C, b1C);
  gemm_proj<128, 0><<<2048, 256, 0, stream>>>(x,   Wih0h, b0C, buf);  // preC0 (P layout)
  rnn_rec<0><<<4, 256, 0, stream>>>(buf, Whh0h, buf, nullptr);        // h1 over pre0
  gemm_proj<256, 1><<<2048, 256, 0, stream>>>(buf, Wih1h, b1C, buf);  // preC1 over h1
  rnn_rec<1><<<4, 256, 0, stream>>>(buf, Whh1h, nullptr, h2last);
  fc_kernel<<<32, 256, 0, stream>>>(h2last, fcw, fcb, out);
}

// Round 8
// 2467.519 us; speedup vs baseline: 2.1518x; 1.3370x over previous
//
#include <hip/hip_runtime.h>

typedef _Float16 f16;
typedef _Float16 f16x4 __attribute__((ext_vector_type(4)));
typedef _Float16 f16x8 __attribute__((ext_vector_type(8)));
typedef __fp16   fp16x2 __attribute__((ext_vector_type(2)));
typedef float    f32x4 __attribute__((ext_vector_type(4)));

#define MFMA_F16(A,B,C) __builtin_amdgcn_mfma_f32_16x16x32_f16((A),(B),(C),0,0,0)

// 2*log2(e): pre-activation is stored pre-scaled by this, so tanh(z) needs only
// exp2: z2 = acc*C2 + preC;  tanh = 1 - 2*rcp(exp2(z2)+1)
#define C2F 2.885390081777927f

// pack 4 floats -> f16x4 via two v_cvt_pkrtz_f16_f32 (bit-identical reinterpret)
__device__ __forceinline__ f16x4 pk4(float a, float b, float c, float d) {
  union { fp16x2 p[2]; f16x4 v; } u;
  u.p[0] = __builtin_amdgcn_cvt_pkrtz(a, b);
  u.p[1] = __builtin_amdgcn_cvt_pkrtz(c, d);
  return u.v;
}

// Physical LDS slot permutation: spreads the b64-write bank pattern while the
// b128 read side (16-lane phases, 16B/lane) stays a bijective slot permutation
// => conflict-free reads.  Bijective XOR of bits{3,4} into bits{2,1}.
__device__ __forceinline__ int pslot(int s) {
  return s ^ (((s >> 3) & 1) << 2) ^ (((s >> 4) & 1) << 1);
}

// Global fragment-pack layout P for pre/h1 (f16):
//   elem(t, b, col) -> t*16384 + (col>>2)*256 + b*4 + (col&3)
// A lane's 4 consecutive cols for one batch = one aligned 8B pack.

// ---------------------------------------------------------------------------
// prep: weights fp32 -> fp16 (row-major), biases combined AND scaled by C2
// ---------------------------------------------------------------------------
__global__ void prep_kernel(const float* __restrict__ Wih0, const float* __restrict__ Whh0,
                            const float* __restrict__ Wih1, const float* __restrict__ Whh1,
                            const float* __restrict__ bih0, const float* __restrict__ bhh0,
                            const float* __restrict__ bih1, const float* __restrict__ bhh1,
                            f16* __restrict__ wdst, float* __restrict__ b0C, float* __restrict__ b1C)
{
  if (blockIdx.x == 224) {
    const int i = threadIdx.x;  // 256 threads
    b0C[i] = (bih0[i] + bhh0[i]) * C2F;
    b1C[i] = (bih1[i] + bhh1[i]) * C2F;
    return;
  }
  const int i4 = (blockIdx.x * 256 + threadIdx.x) * 4;
  const float* src; int off;
  if (i4 < 32768)       { src = Wih0; off = i4; }
  else if (i4 < 98304)  { src = Whh0; off = i4 - 32768; }
  else if (i4 < 163840) { src = Wih1; off = i4 - 98304; }
  else                  { src = Whh1; off = i4 - 163840; }
  const float4 v = *(const float4*)(src + off);
  *(f16x4*)(wdst + i4) = pk4(v.x, v.y, v.z, v.w);
}

// ---------------------------------------------------------------------------
// gemm_proj (swapped operands: A = W rows=outcol, B = input rows): computes
// preC = (inp @ W^T + bias) * C2, stored in P layout (f16).
// MODE 0: inp = x fp32 [64 b][2048 t][128]; block = (b, 64-t tile); KK=128
// MODE 1: inp = h1 (P layout f16), one t-slice per block; KK=256; IN PLACE OK
//         (whole slice staged to LDS before any store; blocks touch disjoint t)
// Per WG: 64 rows x 256 outcols, 4 waves; wave wv owns outcols [wv*64,+64)
// ---------------------------------------------------------------------------
template<int KK, int MODE>
__global__ __launch_bounds__(256, 2)
void gemm_proj(const void* Asrc, const f16* __restrict__ W,
               const float* __restrict__ biasC, f16* outp)
{
  constexpr int NKB = KK / 32;
  __shared__ f16 sB[4 * NKB * 512];  // [rt 0..3][kb][slot 0..63][j8] (linear slots)

  const int tid = threadIdx.x, lane = tid & 63, wv = tid >> 6;
  const int l15 = lane & 15, l4 = lane >> 4;
  const int bid = blockIdx.x;

  if constexpr (MODE == 0) {
    // rows = 64 consecutive t for batch b; stage fp32 -> f16 B-frags
    const float* x = (const float*)Asrc + ((size_t)(bid >> 5) * 2048 + (size_t)(bid & 31) * 64) * 128;
    const int rp = tid >> 3, kg = tid & 7;   // rows 2rp,2rp+1 ; k = kg*16..+15
#pragma unroll
    for (int rr = 0; rr < 2; ++rr) {
      const int row = rp * 2 + rr;
      const float* xr = x + (size_t)row * 128 + kg * 16;
#pragma unroll
      for (int c4 = 0; c4 < 4; ++c4) {
        const float4 v = *(const float4*)(xr + c4 * 4);
        const int k = kg * 16 + c4 * 4;
        const int rt = row >> 4, kb = k >> 5;
        const int slot = (row & 15) + 16 * ((k >> 3) & 3);
        *(f16x4*)&sB[rt * (NKB * 512) + kb * 512 + slot * 8 + (k & 7)] = pk4(v.x, v.y, v.z, v.w);
      }
    }
  } else {
    // one t-slice (16384 f16 = 32KB) in P layout; rows = 64 batches
    const f16* hp = (const f16*)Asrc + (size_t)bid * 16384;
#pragma unroll
    for (int it = 0; it < 8; ++it) {
      const int o = tid * 8 + it * 2048;       // f16 elems; 8 elems = 2 packs
      const f16x8 v = *(const f16x8*)(hp + o);
      const int cp = o >> 8;                   // colpack
      const int b0 = (o >> 2) & 63;            // even; covers b0, b0+1
      const int k0 = cp * 4;
      const int kb = k0 >> 5;
      const int jo = k0 & 7;                   // 0 or 4
      const int qq = (k0 >> 3) & 3;
      f16x4 lo; lo.x = v[0]; lo.y = v[1]; lo.z = v[2]; lo.w = v[3];
      f16x4 hi; hi.x = v[4]; hi.y = v[5]; hi.z = v[6]; hi.w = v[7];
      const int s0 = ((b0 & 15) + 16 * qq), rt0 = b0 >> 4;
      const int s1 = (((b0 + 1) & 15) + 16 * qq), rt1 = (b0 + 1) >> 4;
      *(f16x4*)&sB[rt0 * (NKB * 512) + kb * 512 + s0 * 8 + jo] = lo;
      *(f16x4*)&sB[rt1 * (NKB * 512) + kb * 512 + s1 * 8 + jo] = hi;
    }
  }
  __syncthreads();

  // A-frags: lane holds W[outcol = base+ct*16+l15][k = kb*32 + l4*8 ..+7]
  f16x8 wa[4][NKB];
#pragma unroll
  for (int ct = 0; ct < 4; ++ct) {
    const int oc = wv * 64 + ct * 16 + l15;
#pragma unroll
    for (int kb = 0; kb < NKB; ++kb)
      wa[ct][kb] = *(const f16x8*)(W + (size_t)oc * KK + kb * 32 + l4 * 8);
  }
  float bC[4][4];
#pragma unroll
  for (int ct = 0; ct < 4; ++ct)
#pragma unroll
    for (int r = 0; r < 4; ++r)
      bC[ct][r] = biasC[wv * 64 + ct * 16 + l4 * 4 + r];

  f32x4 acc[4][4];  // [ct][rt]
#pragma unroll
  for (int ct = 0; ct < 4; ++ct)
#pragma unroll
    for (int rt = 0; rt < 4; ++rt)
      acc[ct][rt] = f32x4{0.f, 0.f, 0.f, 0.f};

#pragma unroll
  for (int kb = 0; kb < NKB; ++kb)
#pragma unroll
    for (int rt = 0; rt < 4; ++rt) {
      const f16x8 hb = *(const f16x8*)&sB[rt * (NKB * 512) + kb * 512 + lane * 8];
#pragma unroll
      for (int ct = 0; ct < 4; ++ct)
        acc[ct][rt] = MFMA_F16(wa[ct][kb], hb, acc[ct][rt]);
    }

  // epilogue: C[m=outcol][n=row]; lane holds outcols ct*16+l4*4+r for row rt*16+l15
#pragma unroll
  for (int rt = 0; rt < 4; ++rt) {
    const int rown = rt * 16 + l15;
    size_t base;  // f16 elems into P
    if constexpr (MODE == 0) base = ((size_t)(bid & 31) * 64 + rown) * 16384 + (size_t)(bid >> 5) * 4;
    else                     base = (size_t)bid * 16384 + (size_t)rown * 4;
#pragma unroll
    for (int ct = 0; ct < 4; ++ct) {
      const int cp = wv * 16 + ct * 4 + l4;
      const float v0 = fmaf(acc[ct][rt][0], C2F, bC[ct][0]);
      const float v1 = fmaf(acc[ct][rt][1], C2F, bC[ct][1]);
      const float v2 = fmaf(acc[ct][rt][2], C2F, bC[ct][2]);
      const float v3 = fmaf(acc[ct][rt][3], C2F, bC[ct][3]);
      *(f16x4*)(outp + base + (size_t)cp * 256) = pk4(v0, v1, v2, v3);
    }
  }
}

// ---------------------------------------------------------------------------
// rnn_rec: h_t = tanh-from-exp2(pre[t], h_{t-1} @ Whh^T).
// 4 WGs x 16 batches, 8 WAVES (512 thr, 2 waves/SIMD for latency overlap);
// wave owns 32 outcols (2 ct).  A = Whh frags VGPR-resident (64 regs),
// B = h frags from LDS (linear b128 reads, pslot-permuted slots).  Epilogue:
// 2x (cvt_pkrtz pair -> ds_write_b64 + 8B global store).  pre prefetched 2
// steps ahead.  One s_barrier per step, lgkmcnt-only drain (global ops stay
// in flight).  LAYER 0: hout may alias pre (in-place h1 over pre0).
// ---------------------------------------------------------------------------
template<int LAYER>
__global__ __launch_bounds__(512, 2)
void rnn_rec(const f16* pre,                // P layout [T][cp][b][4]
             const f16* __restrict__ Whh,   // [256][256] f16 row-major
             f16* hout,                     // P layout (LAYER 0; may == pre)
             float* __restrict__ hlast)     // [64][256] f32 (LAYER 1)
{
  __shared__ f16 sH[8192];  // 2 buffers x [8 kb][64 pslot][8 f16]
  const int tid = threadIdx.x, lane = tid & 63, wv = tid >> 6;  // wv 0..7
  const int l15 = lane & 15, l4 = lane >> 4;
  const int g16 = blockIdx.x * 16;

  for (int i = tid; i < 2048; i += 512) ((unsigned int*)sH)[i] = 0u;  // h_{-1}=0 (buf0)

  // Whh A-frags, VGPR-resident: lane holds Whh[wv*32+ct*16+l15][kb*32+l4*8 ..+7]
  f16x8 wa[2][8];
#pragma unroll
  for (int ct = 0; ct < 2; ++ct) {
    const int oc = wv * 32 + ct * 16 + l15;
#pragma unroll
    for (int kb = 0; kb < 8; ++kb)
      wa[ct][kb] = *(const f16x8*)(Whh + (size_t)oc * 256 + kb * 32 + l4 * 8);
  }

  // LDS write offsets (f16 elems): all our cols live in kb'=wv;
  // col = wv*32 + ct*16 + l4*4 + r -> q=(col>>3)&3 = ct*2+(l4>>1), j=(l4&1)*4
  int woff[2];
#pragma unroll
  for (int ct = 0; ct < 2; ++ct) {
    const int q = ct * 2 + (l4 >> 1);
    woff[ct] = wv * 512 + pslot(l15 + 16 * q) * 8 + (l4 & 1) * 4;
  }
  const int roff = pslot(lane) * 8;

  // global P lane offset (f16 elems): cp = wv*8 + ct*4 + l4, b = g16+l15
  const int laneP = (wv * 8 + l4) * 256 + (g16 + l15) * 4;  // + ct*1024 + t*16384

  f16x4 pA[2], pB[2];
#pragma unroll
  for (int ct = 0; ct < 2; ++ct) {
    pA[ct] = *(const f16x4*)(pre + laneP + ct * 1024);            // t=0
    pB[ct] = *(const f16x4*)(pre + 16384 + laneP + ct * 1024);    // t=1
  }
  __syncthreads();

  auto step = [&](int t, int rdo, int wro, f16x4 (&pc)[2], bool last) {
    f32x4 acc[2];
#pragma unroll
    for (int i = 0; i < 2; ++i) acc[i] = f32x4{0.f, 0.f, 0.f, 0.f};
#pragma unroll
    for (int kb = 0; kb < 8; ++kb) {
      const f16x8 hb = *(const f16x8*)&sH[rdo + kb * 512 + roff];
#pragma unroll
      for (int ct = 0; ct < 2; ++ct)
        acc[ct] = MFMA_F16(wa[ct][kb], hb, acc[ct]);
    }
    // consume pre into z2, then refill pc with pre[t+2] (loads issued early)
    float z2[2][4];
#pragma unroll
    for (int ct = 0; ct < 2; ++ct)
#pragma unroll
      for (int r = 0; r < 4; ++r)
        z2[ct][r] = fmaf(acc[ct][r], C2F, (float)pc[ct][r]);
    if (t + 2 < 2048) {
#pragma unroll
      for (int ct = 0; ct < 2; ++ct)
        pc[ct] = *(const f16x4*)(pre + (size_t)(t + 2) * 16384 + laneP + ct * 1024);
    }
#pragma unroll
    for (int ct = 0; ct < 2; ++ct) {
      float h[4];
#pragma unroll
      for (int r = 0; r < 4; ++r) {
        const float e = __builtin_amdgcn_exp2f(z2[ct][r]);
        h[r] = fmaf(__builtin_amdgcn_rcpf(e + 1.0f), -2.0f, 1.0f);
      }
      const f16x4 pk = pk4(h[0], h[1], h[2], h[3]);
      *(f16x4*)&sH[wro + woff[ct]] = pk;
      if constexpr (LAYER == 0) {
        *(f16x4*)(hout + (size_t)t * 16384 + laneP + ct * 1024) = pk;
      } else {
        if (last) {
#pragma unroll
          for (int r = 0; r < 4; ++r)
            hlast[(g16 + l15) * 256 + wv * 32 + ct * 16 + l4 * 4 + r] = h[r];
        }
      }
    }
    // LDS-only drain before barrier: global loads/stores stay in flight
    asm volatile("s_waitcnt lgkmcnt(0)" ::: "memory");
    __builtin_amdgcn_sched_barrier(0);
    __builtin_amdgcn_s_barrier();
    __builtin_amdgcn_sched_barrier(0);
  };

#pragma unroll 1
  for (int t = 0; t < 2048; t += 2) {
    step(t,     0,    4096, pA, false);
    step(t + 1, 4096, 0,    pB, t + 1 == 2047);
  }
}

// ---------------------------------------------------------------------------
// fc: out[b][o] = h2last[b] . fc_w[o] + fc_b[o]
// ---------------------------------------------------------------------------
__global__ void fc_kernel(const float* __restrict__ h, const float* __restrict__ W,
                          const float* __restrict__ bvec, float* __restrict__ out)
{
  const int idx = blockIdx.x * 256 + threadIdx.x;  // 8192
  const int bb = idx >> 7, o = idx & 127;
  const float4* hp = (const float4*)(h + bb * 256);
  const float4* wp = (const float4*)(W + o * 256);
  float acc = 0.f;
#pragma unroll
  for (int i = 0; i < 64; ++i) {
    const float4 a = hp[i], c = wp[i];
    acc += a.x * c.x + a.y * c.y + a.z * c.z + a.w * c.w;
  }
  out[idx] = acc + bvec[o];
}

// ---------------------------------------------------------------------------
extern "C" void kernel_launch(void* const* d_in, const int* in_sizes, int n_in,
                              void* d_out, int out_size, void* d_ws, size_t ws_size,
                              hipStream_t stream)
{
  const float* x    = (const float*)d_in[0];
  const float* Wih0 = (const float*)d_in[1];
  const float* Whh0 = (const float*)d_in[2];
  const float* bih0 = (const float*)d_in[3];
  const float* bhh0 = (const float*)d_in[4];
  const float* Wih1 = (const float*)d_in[5];
  const float* Whh1 = (const float*)d_in[6];
  const float* bih1 = (const float*)d_in[7];
  const float* bhh1 = (const float*)d_in[8];
  const float* fcw  = (const float*)d_in[9];
  const float* fcb  = (const float*)d_in[10];
  float* out = (float*)d_out;

  // Workspace plan (~64.5 MB total)
  char* ws = (char*)d_ws;
  f16*   Wih0h  = (f16*)(ws);             // 64 KB (base for all 4 matrices)
  f16*   Whh0h  = (f16*)(ws + 65536);     // 128 KB
  f16*   Wih1h  = (f16*)(ws + 196608);    // 128 KB
  f16*   Whh1h  = (f16*)(ws + 327680);    // 128 KB
  float* b0C    = (float*)(ws + 458752);  // 1 KB
  float* b1C    = (float*)(ws + 459776);  // 1 KB
  float* h2last = (float*)(ws + 460800);  // 64 KB
  f16*   buf    = (f16*)(ws + 526336);    // 64 MiB: pre0 -> h1 -> pre1 (in place)

  prep_kernel<<<225, 256, 0, stream>>>(Wih0, Whh0, Wih1, Whh1, bih0, bhh0, bih1, bhh1,
                                       Wih0h, b0C, b1C);
  gemm_proj<128, 0><<<2048, 256, 0, stream>>>(x,   Wih0h, b0C, buf);  // preC0 (P layout)
  rnn_rec<0><<<4, 512, 0, stream>>>(buf, Whh0h, buf, nullptr);        // h1 over pre0
  gemm_proj<256, 1><<<2048, 256, 0, stream>>>(buf, Wih1h, b1C, buf);  // preC1 over h1
  rnn_rec<1><<<4, 512, 0, stream>>>(buf, Whh1h, nullptr, h2last);
  fc_kernel<<<32, 256, 0, stream>>>(h2last, fcw, fcb, out);
}